// Round 1
// baseline (366.579 us; speedup 1.0000x reference)
//
#include <hip/hip_runtime.h>
#include <hip/hip_bf16.h>

// 2-layer GAT (PyG GATConv semantics) on MI355X.
// Pipeline: CSR build (deg->scan->scatter, dst-sorted) shared by both layers;
// per layer: GEMM (h = x@W), alpha reduce, per-dst-node aggregate
// (segment softmax + weighted sum), fused bias(+ELU).

#define LRELU_SLOPE 0.2f

// ---------------- CSR build ----------------

__global__ void zero2_kernel(int* __restrict__ a, int* __restrict__ b, int n) {
    int i = blockIdx.x * blockDim.x + threadIdx.x;
    if (i < n) { a[i] = 0; b[i] = 0; }
}

__global__ void degree_kernel(const int* __restrict__ ei, int E, int N,
                              int* __restrict__ deg) {
    int e = blockIdx.x * blockDim.x + threadIdx.x;
    if (e >= E + N) return;
    int d = (e < E) ? ei[E + e] : (e - E);   // self-loop edges appended
    atomicAdd(&deg[d], 1);
}

// single-block exclusive scan over n ints (n ~ 50000), blockDim = 1024
__global__ void scan_kernel(const int* __restrict__ deg, int* __restrict__ row_ptr, int n) {
    __shared__ int sm[16];
    __shared__ int carry_sm;
    int tid = threadIdx.x;
    if (tid == 0) carry_sm = 0;
    __syncthreads();
    int lane = tid & 63, wid = tid >> 6;
    for (int base = 0; base < n; base += 1024) {
        int i = base + tid;
        int v = (i < n) ? deg[i] : 0;
        int s = v;
        #pragma unroll
        for (int o = 1; o < 64; o <<= 1) { int t = __shfl_up(s, o); if (lane >= o) s += t; }
        if (lane == 63) sm[wid] = s;
        __syncthreads();
        if (wid == 0 && lane < 16) {
            int ws = sm[lane];
            #pragma unroll
            for (int o = 1; o < 16; o <<= 1) { int t = __shfl_up(ws, o); if (lane >= o) ws += t; }
            sm[lane] = ws;
        }
        __syncthreads();
        int carry = carry_sm;
        int wpre = (wid > 0) ? sm[wid - 1] : 0;
        int excl = carry + wpre + s - v;
        if (i < n) row_ptr[i] = excl;
        if (i == n - 1) row_ptr[n] = excl + v;
        __syncthreads();
        if (tid == 0) carry_sm = carry + sm[15];
        __syncthreads();
    }
}

__global__ void scatter_kernel(const int* __restrict__ ei, int E, int N,
                               const int* __restrict__ row_ptr,
                               int* __restrict__ cnt, int* __restrict__ srcs) {
    int e = blockIdx.x * blockDim.x + threadIdx.x;
    if (e >= E + N) return;
    int s, d;
    if (e < E) { s = ei[e]; d = ei[E + e]; }
    else       { s = e - E; d = s; }
    int pos = row_ptr[d] + atomicAdd(&cnt[d], 1);
    srcs[pos] = s;
}

// ---------------- GEMM: Y[M x NCOLS] = X[M x 128] @ W[128 x NCOLS] ----------------
// block = 256 threads, 32 rows per block, X tile staged in LDS, W streamed (L1/L2).

template<int NCOLS>
__global__ void gemm_kernel(const float* __restrict__ X, const float* __restrict__ W,
                            float* __restrict__ Y, int M) {
    constexpr int K = 128;
    constexpr int ROWS = 32;
    constexpr int G = 256 / NCOLS;      // row groups
    constexpr int RPT = ROWS / G;       // rows per thread
    __shared__ float xs[ROWS * K];
    int tid = threadIdx.x;
    int row0 = blockIdx.x * ROWS;
    for (int j = tid; j < ROWS * K; j += 256) {
        int r = j >> 7;        // j / K
        int k = j & (K - 1);
        int gr = row0 + r;
        xs[j] = (gr < M) ? X[gr * K + k] : 0.f;
    }
    __syncthreads();
    int c  = tid % NCOLS;
    int rg = tid / NCOLS;
    int rbase = rg * RPT;
    float acc[RPT];
    #pragma unroll
    for (int i = 0; i < RPT; i++) acc[i] = 0.f;
    #pragma unroll 8
    for (int k = 0; k < K; k++) {
        float w = W[k * NCOLS + c];
        #pragma unroll
        for (int i = 0; i < RPT; i++) acc[i] += xs[(rbase + i) * K + k] * w;
    }
    #pragma unroll
    for (int i = 0; i < RPT; i++) {
        int gr = row0 + rbase + i;
        if (gr < M) Y[gr * NCOLS + c] = acc[i];
    }
}

// ---------------- alpha = einsum('nhf,hf->nh') ----------------
// one node per block, HF threads (HF = heads*64); each 64-lane wave = one head.

__global__ void alpha_kernel(const float* __restrict__ h, const float* __restrict__ aw_s,
                             const float* __restrict__ aw_d, float* __restrict__ os,
                             float* __restrict__ od, int HF) {
    int n = blockIdx.x;
    int tid = threadIdx.x;
    float hv = h[n * HF + tid];
    float ps = hv * aw_s[tid];
    float pd = hv * aw_d[tid];
    #pragma unroll
    for (int o = 32; o > 0; o >>= 1) { ps += __shfl_xor(ps, o); pd += __shfl_xor(pd, o); }
    if ((tid & 63) == 0) {
        int hidx = tid >> 6;
        int heads = HF >> 6;
        os[n * heads + hidx] = ps;
        od[n * heads + hidx] = pd;
    }
}

// ---------------- aggregate: segment softmax + weighted gather-sum ----------------
// one dst node per block, HF threads; lane f owns feature f, head h = f>>6.
// denom needs no cross-lane reduce: all 64 lanes of a head compute identical w.

template<int HF, bool DO_ELU>
__global__ void aggregate_kernel(const float* __restrict__ hin,
                                 const float* __restrict__ asrc,
                                 const float* __restrict__ adst,
                                 const int* __restrict__ row_ptr,
                                 const int* __restrict__ srcs,
                                 const float* __restrict__ bias,
                                 float* __restrict__ out, int N) {
    constexpr int HEADS = HF / 64;
    int n = blockIdx.x;
    int tid = threadIdx.x;
    int h = tid >> 6;
    int lane = tid & 63;
    int start = row_ptr[n], end = row_ptr[n + 1];
    float ad = adst[n * HEADS + h];
    // pass 1: per-head max over incoming edges (each wave covers ALL edges)
    float m = -3.0e38f;
    for (int i = start + lane; i < end; i += 64) {
        int s = srcs[i];
        float e = asrc[s * HEADS + h] + ad;
        e = (e >= 0.f) ? e : LRELU_SLOPE * e;
        m = fmaxf(m, e);
    }
    #pragma unroll
    for (int o = 32; o > 0; o >>= 1) m = fmaxf(m, __shfl_xor(m, o));
    // pass 2: accumulate exp-weighted features + denom
    float dsum = 0.f, acc = 0.f;
    for (int i = start; i < end; i++) {
        int s = srcs[i];
        float e = asrc[s * HEADS + h] + ad;
        e = (e >= 0.f) ? e : LRELU_SLOPE * e;
        float w = __expf(e - m);
        dsum += w;
        acc += w * hin[s * HF + tid];
    }
    float v = acc / dsum + bias[tid];
    if (DO_ELU) v = (v > 0.f) ? v : (__expf(v) - 1.f);
    out[n * HF + tid] = v;
}

// ---------------- launch ----------------

extern "C" void kernel_launch(void* const* d_in, const int* in_sizes, int n_in,
                              void* d_out, int out_size, void* d_ws, size_t ws_size,
                              hipStream_t stream) {
    const float* x    = (const float*)d_in[0];
    const int*   ei   = (const int*)d_in[1];
    const float* W1   = (const float*)d_in[2];
    const float* as1w = (const float*)d_in[3];
    const float* ad1w = (const float*)d_in[4];
    const float* b1   = (const float*)d_in[5];
    const float* W2   = (const float*)d_in[6];
    const float* as2w = (const float*)d_in[7];
    const float* ad2w = (const float*)d_in[8];
    const float* b2   = (const float*)d_in[9];
    float* out = (float*)d_out;

    const int N  = in_sizes[0] / 128;   // 50000
    const int E  = in_sizes[1] / 2;     // 600000
    const int ET = E + N;               // with self loops

    // workspace carve
    char* base = (char*)d_ws;
    size_t off = 0;
    auto alloc = [&](size_t bytes) -> void* {
        void* p = base + off;
        off += (bytes + 255) & ~(size_t)255;
        return p;
    };
    float* h1      = (float*)alloc((size_t)N * 128 * 4);
    float* helu    = (float*)alloc((size_t)N * 128 * 4);
    float* h2      = (float*)alloc((size_t)N * 64 * 4);
    float* as1     = (float*)alloc((size_t)N * 2 * 4);
    float* ad1     = (float*)alloc((size_t)N * 2 * 4);
    float* as2     = (float*)alloc((size_t)N * 4);
    float* ad2     = (float*)alloc((size_t)N * 4);
    int*   deg     = (int*)alloc((size_t)N * 4);
    int*   cnt     = (int*)alloc((size_t)N * 4);
    int*   row_ptr = (int*)alloc((size_t)(N + 1) * 4);
    int*   srcs    = (int*)alloc((size_t)ET * 4);

    // CSR build (same graph for both layers)
    zero2_kernel<<<(N + 255) / 256, 256, 0, stream>>>(deg, cnt, N);
    degree_kernel<<<(ET + 255) / 256, 256, 0, stream>>>(ei, E, N, deg);
    scan_kernel<<<1, 1024, 0, stream>>>(deg, row_ptr, N);
    scatter_kernel<<<(ET + 255) / 256, 256, 0, stream>>>(ei, E, N, row_ptr, cnt, srcs);

    // layer 1: heads=2, out_dim=64, concat -> [N,128], ELU
    gemm_kernel<128><<<(N + 31) / 32, 256, 0, stream>>>(x, W1, h1, N);
    alpha_kernel<<<N, 128, 0, stream>>>(h1, as1w, ad1w, as1, ad1, 128);
    aggregate_kernel<128, true><<<N, 128, 0, stream>>>(h1, as1, ad1, row_ptr, srcs, b1, helu, N);

    // layer 2: heads=1, out_dim=64, mean over 1 head == identity
    gemm_kernel<64><<<(N + 31) / 32, 256, 0, stream>>>(helu, W2, h2, N);
    alpha_kernel<<<N, 64, 0, stream>>>(h2, as2w, ad2w, as2, ad2, 64);
    aggregate_kernel<64, false><<<N, 64, 0, stream>>>(h2, as2, ad2, row_ptr, srcs, b2, out, N);
}

// Round 2
// 217.526 us; speedup vs baseline: 1.6852x; 1.6852x over previous
//
#include <hip/hip_runtime.h>
#include <hip/hip_bf16.h>

// 2-layer GAT on MI355X. R2: wave-per-node aggregates with LDS-cached edge
// weights + unroll-4 gather (bf16 for layer1), 4x4-register-tile f32 GEMM,
// multi-block scan.

#define LRELU_SLOPE 0.2f
#define CAP 128   // per-node LDS edge cache; deg>CAP falls back to recompute

// ---------------- CSR build ----------------

__global__ void zero2_kernel(int* __restrict__ a, int* __restrict__ b, int n) {
    int i = blockIdx.x * blockDim.x + threadIdx.x;
    if (i < n) { a[i] = 0; b[i] = 0; }
}

__global__ void degree_kernel(const int* __restrict__ ei, int E, int N,
                              int* __restrict__ deg) {
    int e = blockIdx.x * blockDim.x + threadIdx.x;
    if (e >= E + N) return;
    int d = (e < E) ? ei[E + e] : (e - E);   // self-loop edges appended
    atomicAdd(&deg[d], 1);
}

// scan phase 1: each 1024-block scans its chunk, writes local-exclusive to
// row_ptr[i] and the block total to bsum[blockIdx].
__global__ void scan1_kernel(const int* __restrict__ deg, int* __restrict__ row_ptr,
                             int* __restrict__ bsum, int n) {
    __shared__ int sm[16];
    int tid = threadIdx.x;
    int i = blockIdx.x * 1024 + tid;
    int v = (i < n) ? deg[i] : 0;
    int lane = tid & 63, wid = tid >> 6;
    int s = v;
    #pragma unroll
    for (int o = 1; o < 64; o <<= 1) { int t = __shfl_up(s, o); if (lane >= o) s += t; }
    if (lane == 63) sm[wid] = s;
    __syncthreads();
    if (tid < 16) {
        int ws = sm[tid];
        #pragma unroll
        for (int o = 1; o < 16; o <<= 1) { int t = __shfl_up(ws, o); if (tid >= o) ws += t; }
        sm[tid] = ws;
    }
    __syncthreads();
    int excl = (wid ? sm[wid - 1] : 0) + s - v;
    if (i < n) row_ptr[i] = excl;
    if (tid == 1023) bsum[blockIdx.x] = excl + v;
}

// scan phase 2: single wave exclusive-scans the <=64 block sums in place.
__global__ void scan2_kernel(int* __restrict__ bsum, int nb) {
    int tid = threadIdx.x;   // 64
    int v = (tid < nb) ? bsum[tid] : 0;
    int s = v;
    #pragma unroll
    for (int o = 1; o < 64; o <<= 1) { int t = __shfl_up(s, o); if (tid >= o) s += t; }
    if (tid < nb) bsum[tid] = s - v;
}

// scan phase 3: add block offsets; thread at n-1 writes row_ptr[n].
__global__ void scan3_kernel(int* __restrict__ row_ptr, const int* __restrict__ bsum,
                             const int* __restrict__ deg, int n) {
    int i = blockIdx.x * 1024 + threadIdx.x;
    if (i >= n) return;
    int val = row_ptr[i] + bsum[blockIdx.x];
    row_ptr[i] = val;
    if (i == n - 1) row_ptr[n] = val + deg[i];
}

__global__ void scatter_kernel(const int* __restrict__ ei, int E, int N,
                               const int* __restrict__ row_ptr,
                               int* __restrict__ cnt, int* __restrict__ srcs) {
    int e = blockIdx.x * blockDim.x + threadIdx.x;
    if (e >= E + N) return;
    int s, d;
    if (e < E) { s = ei[e]; d = ei[E + e]; }
    else       { s = e - E; d = s; }
    int pos = row_ptr[d] + atomicAdd(&cnt[d], 1);
    srcs[pos] = s;
}

// ---------------- GEMM: Y[M x NCOLS] = X[M x 128] @ W[128 x NCOLS] ----------------
// 64x64 tile per block (256 threads), 4x4 register tile per thread.
// xs,ws k-major in LDS; xs staged m-major (conflict-free writes), ws coalesced.

template<int NCOLS>
__global__ __launch_bounds__(256) void gemm_kernel(const float* __restrict__ X,
                                                   const float* __restrict__ W,
                                                   float* __restrict__ Y, int M) {
    constexpr int K = 128;
    __shared__ float xs[K * 64];   // [k][m]
    __shared__ float ws[K * 64];   // [k][c]
    int tid = threadIdx.x;
    int row0 = blockIdx.x * 64;
    int cblk = blockIdx.y * 64;

    {   // stage X (transpose rows->k-major)
        int m = tid & 63;
        int kq0 = tid >> 6;          // 0..3
        int gr = row0 + m;
        const float4* Xv = (const float4*)(X + (size_t)gr * K);
        #pragma unroll
        for (int kq = kq0; kq < 32; kq += 4) {
            float4 v = make_float4(0.f, 0.f, 0.f, 0.f);
            if (gr < M) v = Xv[kq];
            int k = kq * 4;
            xs[(k + 0) * 64 + m] = v.x;
            xs[(k + 1) * 64 + m] = v.y;
            xs[(k + 2) * 64 + m] = v.z;
            xs[(k + 3) * 64 + m] = v.w;
        }
    }
    {   // stage W (already k-major)
        int cq = tid & 15;
        int k0 = tid >> 4;           // 0..15
        #pragma unroll
        for (int k = k0; k < K; k += 16) {
            *(float4*)&ws[k * 64 + cq * 4] =
                *(const float4*)(W + (size_t)k * NCOLS + cblk + cq * 4);
        }
    }
    __syncthreads();

    int tc = tid & 15, tr = tid >> 4;
    float acc[4][4];
    #pragma unroll
    for (int i = 0; i < 4; i++)
        #pragma unroll
        for (int j = 0; j < 4; j++) acc[i][j] = 0.f;

    #pragma unroll 8
    for (int k = 0; k < K; k++) {
        float4 a = *(const float4*)&xs[k * 64 + tr * 4];
        float4 b = *(const float4*)&ws[k * 64 + tc * 4];
        float av[4] = {a.x, a.y, a.z, a.w};
        float bv[4] = {b.x, b.y, b.z, b.w};
        #pragma unroll
        for (int i = 0; i < 4; i++)
            #pragma unroll
            for (int j = 0; j < 4; j++) acc[i][j] += av[i] * bv[j];
    }

    #pragma unroll
    for (int i = 0; i < 4; i++) {
        int gr = row0 + tr * 4 + i;
        if (gr < M)
            *(float4*)&Y[(size_t)gr * NCOLS + cblk + tc * 4] =
                make_float4(acc[i][0], acc[i][1], acc[i][2], acc[i][3]);
    }
}

// ---------------- alpha reduces ----------------
// layer1: also emits bf16 copy of h for the gather. 256 thr = 2 nodes.

__global__ void alpha1_kernel(const float* __restrict__ h, const float* __restrict__ aw_s,
                              const float* __restrict__ aw_d, float* __restrict__ os,
                              float* __restrict__ od, __hip_bfloat16* __restrict__ hb) {
    int tid = threadIdx.x;
    int n = blockIdx.x * 2 + (tid >> 7);
    int t = tid & 127;
    float hv = h[(size_t)n * 128 + t];
    hb[(size_t)n * 128 + t] = __float2bfloat16(hv);
    float ps = hv * aw_s[t];
    float pd = hv * aw_d[t];
    #pragma unroll
    for (int o = 32; o > 0; o >>= 1) { ps += __shfl_xor(ps, o); pd += __shfl_xor(pd, o); }
    if ((t & 63) == 0) {
        int hd = t >> 6;
        os[n * 2 + hd] = ps;
        od[n * 2 + hd] = pd;
    }
}

// layer2: HF=64, 256 thr = 4 nodes.
__global__ void alpha2_kernel(const float* __restrict__ h, const float* __restrict__ aw_s,
                              const float* __restrict__ aw_d, float* __restrict__ os,
                              float* __restrict__ od) {
    int tid = threadIdx.x;
    int n = blockIdx.x * 4 + (tid >> 6);
    int l = tid & 63;
    float hv = h[(size_t)n * 64 + l];
    float ps = hv * aw_s[l];
    float pd = hv * aw_d[l];
    #pragma unroll
    for (int o = 32; o > 0; o >>= 1) { ps += __shfl_xor(ps, o); pd += __shfl_xor(pd, o); }
    if (l == 0) { os[n] = ps; od[n] = pd; }
}

// ---------------- aggregates ----------------
// Layer 1: HEADS=2, HF=128, bf16 gather. One wave per node; lane owns
// features {2l, 2l+1}; head = l>>5. srcs + lrelu(e) cached in LDS in pass 1;
// pass 2 unrolled x4 for memory-level parallelism.

__device__ __forceinline__ float bflo(unsigned u) { return __uint_as_float(u << 16); }
__device__ __forceinline__ float bfhi(unsigned u) { return __uint_as_float(u & 0xffff0000u); }

__global__ __launch_bounds__(256) void agg1_kernel(const unsigned* __restrict__ hb,
        const float* __restrict__ asrc, const float* __restrict__ adst,
        const int* __restrict__ row_ptr, const int* __restrict__ srcs,
        const float* __restrict__ bias, float* __restrict__ out, int N) {
    __shared__ int   ssm[4][CAP];
    __shared__ float esm[4][2][CAP];
    int tid = threadIdx.x, wid = tid >> 6, lane = tid & 63;
    int n = blockIdx.x * 4 + wid;
    if (n >= N) return;
    int head = lane >> 5;
    int start = row_ptr[n];
    int deg = row_ptr[n + 1] - start;
    float2 adv = *(const float2*)&adst[n * 2];

    float m0 = -3.0e38f, m1 = -3.0e38f;
    for (int i = lane; i < deg; i += 64) {
        int s = srcs[start + i];
        float2 av = *(const float2*)&asrc[s * 2];
        float e0 = av.x + adv.x; e0 = (e0 >= 0.f) ? e0 : LRELU_SLOPE * e0;
        float e1 = av.y + adv.y; e1 = (e1 >= 0.f) ? e1 : LRELU_SLOPE * e1;
        if (i < CAP) { ssm[wid][i] = s; esm[wid][0][i] = e0; esm[wid][1][i] = e1; }
        m0 = fmaxf(m0, e0); m1 = fmaxf(m1, e1);
    }
    #pragma unroll
    for (int o = 32; o > 0; o >>= 1) {
        m0 = fmaxf(m0, __shfl_xor(m0, o));
        m1 = fmaxf(m1, __shfl_xor(m1, o));
    }
    float mh = head ? m1 : m0;

    float acc0 = 0.f, acc1 = 0.f, dsum = 0.f;
    int nc = (deg < CAP) ? deg : CAP;
    int i = 0;
    for (; i + 4 <= nc; i += 4) {
        int s0 = ssm[wid][i], s1 = ssm[wid][i + 1], s2 = ssm[wid][i + 2], s3 = ssm[wid][i + 3];
        unsigned u0 = hb[(size_t)s0 * 64 + lane];
        unsigned u1 = hb[(size_t)s1 * 64 + lane];
        unsigned u2 = hb[(size_t)s2 * 64 + lane];
        unsigned u3 = hb[(size_t)s3 * 64 + lane];
        float w0 = __expf(esm[wid][head][i]     - mh);
        float w1 = __expf(esm[wid][head][i + 1] - mh);
        float w2 = __expf(esm[wid][head][i + 2] - mh);
        float w3 = __expf(esm[wid][head][i + 3] - mh);
        dsum += (w0 + w1) + (w2 + w3);
        acc0 += w0 * bflo(u0) + w1 * bflo(u1) + w2 * bflo(u2) + w3 * bflo(u3);
        acc1 += w0 * bfhi(u0) + w1 * bfhi(u1) + w2 * bfhi(u2) + w3 * bfhi(u3);
    }
    for (; i < nc; i++) {
        int s = ssm[wid][i];
        unsigned u = hb[(size_t)s * 64 + lane];
        float w = __expf(esm[wid][head][i] - mh);
        dsum += w; acc0 += w * bflo(u); acc1 += w * bfhi(u);
    }
    for (int j = CAP; j < deg; j++) {   // rare fallback
        int s = srcs[start + j];
        float e = asrc[s * 2 + head] + (head ? adv.y : adv.x);
        e = (e >= 0.f) ? e : LRELU_SLOPE * e;
        float w = __expf(e - mh);
        unsigned u = hb[(size_t)s * 64 + lane];
        dsum += w; acc0 += w * bflo(u); acc1 += w * bfhi(u);
    }

    int f0 = 2 * lane;
    float v0 = acc0 / dsum + bias[f0];
    float v1 = acc1 / dsum + bias[f0 + 1];
    v0 = (v0 > 0.f) ? v0 : __expf(v0) - 1.f;   // ELU
    v1 = (v1 > 0.f) ? v1 : __expf(v1) - 1.f;
    *(float2*)&out[(size_t)n * 128 + f0] = make_float2(v0, v1);
}

// Layer 2: HEADS=1, HF=64, f32 gather, lane = feature. No ELU, + bias.
__global__ __launch_bounds__(256) void agg2_kernel(const float* __restrict__ h2,
        const float* __restrict__ asrc, const float* __restrict__ adst,
        const int* __restrict__ row_ptr, const int* __restrict__ srcs,
        const float* __restrict__ bias, float* __restrict__ out, int N) {
    __shared__ int   ssm[4][CAP];
    __shared__ float esm[4][CAP];
    int tid = threadIdx.x, wid = tid >> 6, lane = tid & 63;
    int n = blockIdx.x * 4 + wid;
    if (n >= N) return;
    int start = row_ptr[n];
    int deg = row_ptr[n + 1] - start;
    float ad = adst[n];

    float m = -3.0e38f;
    for (int i = lane; i < deg; i += 64) {
        int s = srcs[start + i];
        float e = asrc[s] + ad;
        e = (e >= 0.f) ? e : LRELU_SLOPE * e;
        if (i < CAP) { ssm[wid][i] = s; esm[wid][i] = e; }
        m = fmaxf(m, e);
    }
    #pragma unroll
    for (int o = 32; o > 0; o >>= 1) m = fmaxf(m, __shfl_xor(m, o));

    float acc = 0.f, dsum = 0.f;
    int nc = (deg < CAP) ? deg : CAP;
    int i = 0;
    for (; i + 4 <= nc; i += 4) {
        int s0 = ssm[wid][i], s1 = ssm[wid][i + 1], s2 = ssm[wid][i + 2], s3 = ssm[wid][i + 3];
        float f0 = h2[(size_t)s0 * 64 + lane];
        float f1 = h2[(size_t)s1 * 64 + lane];
        float f2 = h2[(size_t)s2 * 64 + lane];
        float f3 = h2[(size_t)s3 * 64 + lane];
        float w0 = __expf(esm[wid][i]     - m);
        float w1 = __expf(esm[wid][i + 1] - m);
        float w2 = __expf(esm[wid][i + 2] - m);
        float w3 = __expf(esm[wid][i + 3] - m);
        dsum += (w0 + w1) + (w2 + w3);
        acc += w0 * f0 + w1 * f1 + w2 * f2 + w3 * f3;
    }
    for (; i < nc; i++) {
        int s = ssm[wid][i];
        float w = __expf(esm[wid][i] - m);
        dsum += w; acc += w * h2[(size_t)s * 64 + lane];
    }
    for (int j = CAP; j < deg; j++) {   // rare fallback
        int s = srcs[start + j];
        float e = asrc[s] + ad;
        e = (e >= 0.f) ? e : LRELU_SLOPE * e;
        float w = __expf(e - m);
        dsum += w; acc += w * h2[(size_t)s * 64 + lane];
    }
    out[(size_t)n * 64 + lane] = acc / dsum + bias[lane];
}

// ---------------- launch ----------------

extern "C" void kernel_launch(void* const* d_in, const int* in_sizes, int n_in,
                              void* d_out, int out_size, void* d_ws, size_t ws_size,
                              hipStream_t stream) {
    const float* x    = (const float*)d_in[0];
    const int*   ei   = (const int*)d_in[1];
    const float* W1   = (const float*)d_in[2];
    const float* as1w = (const float*)d_in[3];
    const float* ad1w = (const float*)d_in[4];
    const float* b1   = (const float*)d_in[5];
    const float* W2   = (const float*)d_in[6];
    const float* as2w = (const float*)d_in[7];
    const float* ad2w = (const float*)d_in[8];
    const float* b2   = (const float*)d_in[9];
    float* out = (float*)d_out;

    const int N  = in_sizes[0] / 128;   // 50000
    const int E  = in_sizes[1] / 2;     // 600000
    const int ET = E + N;

    // workspace carve (h1/helu alias; hb1/h2 alias)
    char* base = (char*)d_ws;
    size_t off = 0;
    auto alloc = [&](size_t bytes) -> void* {
        void* p = base + off;
        off += (bytes + 255) & ~(size_t)255;
        return p;
    };
    float* h1      = (float*)alloc((size_t)N * 128 * 4);   // also helu (agg1 output)
    void*  hbws    = alloc((size_t)N * 128 * 2);           // bf16 h1; later f32 h2? no:
    float* h2      = (float*)alloc((size_t)N * 64 * 4);
    float* as1     = (float*)alloc((size_t)N * 2 * 4);
    float* ad1     = (float*)alloc((size_t)N * 2 * 4);
    float* as2     = (float*)alloc((size_t)N * 4);
    float* ad2     = (float*)alloc((size_t)N * 4);
    int*   deg     = (int*)alloc((size_t)N * 4);
    int*   cnt     = (int*)alloc((size_t)N * 4);
    int*   row_ptr = (int*)alloc((size_t)(N + 1) * 4);
    int*   srcs    = (int*)alloc((size_t)ET * 4);
    int*   bsum    = (int*)alloc(64 * 4);
    float* helu    = h1;                       // h1 dead after alpha1
    __hip_bfloat16* hb1 = (__hip_bfloat16*)hbws;

    const int SCAN_B = (N + 1023) / 1024;      // 49

    // CSR build
    zero2_kernel<<<(N + 255) / 256, 256, 0, stream>>>(deg, cnt, N);
    degree_kernel<<<(ET + 255) / 256, 256, 0, stream>>>(ei, E, N, deg);
    scan1_kernel<<<SCAN_B, 1024, 0, stream>>>(deg, row_ptr, bsum, N);
    scan2_kernel<<<1, 64, 0, stream>>>(bsum, SCAN_B);
    scan3_kernel<<<SCAN_B, 1024, 0, stream>>>(row_ptr, bsum, deg, N);
    scatter_kernel<<<(ET + 255) / 256, 256, 0, stream>>>(ei, E, N, row_ptr, cnt, srcs);

    // layer 1: heads=2, out_dim=64, concat -> [N,128], ELU
    gemm_kernel<128><<<dim3((N + 63) / 64, 2), 256, 0, stream>>>(x, W1, h1, N);
    alpha1_kernel<<<N / 2, 256, 0, stream>>>(h1, as1w, ad1w, as1, ad1, hb1);
    agg1_kernel<<<(N + 3) / 4, 256, 0, stream>>>((const unsigned*)hb1, as1, ad1,
                                                 row_ptr, srcs, b1, helu, N);

    // layer 2: heads=1, out_dim=64
    gemm_kernel<64><<<dim3((N + 63) / 64, 1), 256, 0, stream>>>(helu, W2, h2, N);
    alpha2_kernel<<<N / 4, 256, 0, stream>>>(h2, as2w, ad2w, as2, ad2);
    agg2_kernel<<<(N + 3) / 4, 256, 0, stream>>>(h2, as2, ad2, row_ptr, srcs, b2, out, N);
}

// Round 4
// 206.403 us; speedup vs baseline: 1.7760x; 1.0539x over previous
//
#include <hip/hip_runtime.h>
#include <hip/hip_bf16.h>

// 2-layer GAT on MI355X. R4 = R3 + compile fix (float2 cast at agg2 call).
// Alpha fused into GEMM epilogues (no f32 h1), single-pass LDS-free
// aggregates (no segment-max; 32 lanes/edge x 2 edges per wave iteration,
// unroll x2), 10 kernels total.

#define LRELU_SLOPE 0.2f

// ---------------- CSR build ----------------

__global__ void zero2_kernel(int* __restrict__ a, int* __restrict__ b, int n) {
    int i = blockIdx.x * blockDim.x + threadIdx.x;
    if (i < n) { a[i] = 0; b[i] = 0; }
}

__global__ void degree_kernel(const int* __restrict__ ei, int E, int N,
                              int* __restrict__ deg) {
    int e = blockIdx.x * blockDim.x + threadIdx.x;
    if (e >= E + N) return;
    int d = (e < E) ? ei[E + e] : (e - E);   // self-loop edges appended
    atomicAdd(&deg[d], 1);
}

__global__ void scan1_kernel(const int* __restrict__ deg, int* __restrict__ row_ptr,
                             int* __restrict__ bsum, int n) {
    __shared__ int sm[16];
    int tid = threadIdx.x;
    int i = blockIdx.x * 1024 + tid;
    int v = (i < n) ? deg[i] : 0;
    int lane = tid & 63, wid = tid >> 6;
    int s = v;
    #pragma unroll
    for (int o = 1; o < 64; o <<= 1) { int t = __shfl_up(s, o); if (lane >= o) s += t; }
    if (lane == 63) sm[wid] = s;
    __syncthreads();
    if (tid < 16) {
        int ws = sm[tid];
        #pragma unroll
        for (int o = 1; o < 16; o <<= 1) { int t = __shfl_up(ws, o); if (tid >= o) ws += t; }
        sm[tid] = ws;
    }
    __syncthreads();
    int excl = (wid ? sm[wid - 1] : 0) + s - v;
    if (i < n) row_ptr[i] = excl;
    if (tid == 1023) bsum[blockIdx.x] = excl + v;
}

__global__ void scan2_kernel(int* __restrict__ bsum, int nb) {
    int tid = threadIdx.x;   // 64
    int v = (tid < nb) ? bsum[tid] : 0;
    int s = v;
    #pragma unroll
    for (int o = 1; o < 64; o <<= 1) { int t = __shfl_up(s, o); if (tid >= o) s += t; }
    if (tid < nb) bsum[tid] = s - v;
}

__global__ void scan3_kernel(int* __restrict__ row_ptr, const int* __restrict__ bsum,
                             const int* __restrict__ deg, int n) {
    int i = blockIdx.x * 1024 + threadIdx.x;
    if (i >= n) return;
    int val = row_ptr[i] + bsum[blockIdx.x];
    row_ptr[i] = val;
    if (i == n - 1) row_ptr[n] = val + deg[i];
}

__global__ void scatter_kernel(const int* __restrict__ ei, int E, int N,
                               const int* __restrict__ row_ptr,
                               int* __restrict__ cnt, int* __restrict__ srcs) {
    int e = blockIdx.x * blockDim.x + threadIdx.x;
    if (e >= E + N) return;
    int s, d;
    if (e < E) { s = ei[e]; d = ei[E + e]; }
    else       { s = e - E; d = s; }
    int pos = row_ptr[d] + atomicAdd(&cnt[d], 1);
    srcs[pos] = s;
}

// ---------------- bf16 helpers ----------------

__device__ __forceinline__ unsigned short bf16r(float x) {   // RNE
    unsigned u = __float_as_uint(x);
    return (unsigned short)((u + 0x7fff + ((u >> 16) & 1)) >> 16);
}
__device__ __forceinline__ unsigned pbf(float a, float b) {
    return (unsigned)bf16r(a) | ((unsigned)bf16r(b) << 16);
}
__device__ __forceinline__ float bflo(unsigned u) { return __uint_as_float(u << 16); }
__device__ __forceinline__ float bfhi(unsigned u) { return __uint_as_float(u & 0xffff0000u); }

// ---------------- layer-1 GEMM + alpha + bf16 emit ----------------
// 64 rows x 64 cols per block (blockIdx.y = head); 4x4 register tile.
// Epilogue: per-row alpha reduce across the 16 tc-threads (shfl within wave),
// h written ONLY as bf16 (gather format), f32 h never materialized.

__global__ __launch_bounds__(256) void gemm1_kernel(const float* __restrict__ X,
        const float* __restrict__ W, const float* __restrict__ asw,
        const float* __restrict__ adw, uint2* __restrict__ hb,
        float* __restrict__ as_out, float* __restrict__ ad_out, int M) {
    constexpr int K = 128, NCOLS = 128;
    __shared__ float xs[K * 64];   // [k][m]
    __shared__ float ws[K * 64];   // [k][c]
    int tid = threadIdx.x;
    int row0 = blockIdx.x * 64;
    int head = blockIdx.y;
    int cblk = head * 64;

    {   // stage X (transpose to k-major)
        int m = tid & 63;
        int kq0 = tid >> 6;
        int gr = row0 + m;
        const float4* Xv = (const float4*)(X + (size_t)gr * K);
        #pragma unroll
        for (int kq = kq0; kq < 32; kq += 4) {
            float4 v = make_float4(0.f, 0.f, 0.f, 0.f);
            if (gr < M) v = Xv[kq];
            int k = kq * 4;
            xs[(k + 0) * 64 + m] = v.x;
            xs[(k + 1) * 64 + m] = v.y;
            xs[(k + 2) * 64 + m] = v.z;
            xs[(k + 3) * 64 + m] = v.w;
        }
    }
    {   // stage W slab (k-major already)
        int cq = tid & 15;
        int k0 = tid >> 4;
        #pragma unroll
        for (int k = k0; k < K; k += 16) {
            *(float4*)&ws[k * 64 + cq * 4] =
                *(const float4*)(W + (size_t)k * NCOLS + cblk + cq * 4);
        }
    }
    __syncthreads();

    int tc = tid & 15, tr = tid >> 4;
    float acc[4][4];
    #pragma unroll
    for (int i = 0; i < 4; i++)
        #pragma unroll
        for (int j = 0; j < 4; j++) acc[i][j] = 0.f;

    #pragma unroll 8
    for (int k = 0; k < K; k++) {
        float4 a = *(const float4*)&xs[k * 64 + tr * 4];
        float4 b = *(const float4*)&ws[k * 64 + tc * 4];
        float av[4] = {a.x, a.y, a.z, a.w};
        float bv[4] = {b.x, b.y, b.z, b.w};
        #pragma unroll
        for (int i = 0; i < 4; i++)
            #pragma unroll
            for (int j = 0; j < 4; j++) acc[i][j] += av[i] * bv[j];
    }

    // epilogue: alpha partials + bf16 h
    float av[4], dv[4];
    #pragma unroll
    for (int j = 0; j < 4; j++) {
        av[j] = asw[cblk + tc * 4 + j];
        dv[j] = adw[cblk + tc * 4 + j];
    }
    #pragma unroll
    for (int i = 0; i < 4; i++) {
        float ps = acc[i][0] * av[0] + acc[i][1] * av[1] + acc[i][2] * av[2] + acc[i][3] * av[3];
        float pd = acc[i][0] * dv[0] + acc[i][1] * dv[1] + acc[i][2] * dv[2] + acc[i][3] * dv[3];
        #pragma unroll
        for (int o = 1; o < 16; o <<= 1) { ps += __shfl_xor(ps, o); pd += __shfl_xor(pd, o); }
        int gr = row0 + tr * 4 + i;
        if (gr < M) {
            if (tc == 0) { as_out[gr * 2 + head] = ps; ad_out[gr * 2 + head] = pd; }
            hb[(size_t)gr * 32 + head * 16 + tc] =
                make_uint2(pbf(acc[i][0], acc[i][1]), pbf(acc[i][2], acc[i][3]));
        }
    }
}

// ---------------- layer-2 GEMM + alpha ----------------
// NCOLS=64, single head; writes f32 h2 + as2/ad2.

__global__ __launch_bounds__(256) void gemm2_kernel(const float* __restrict__ X,
        const float* __restrict__ W, const float* __restrict__ asw,
        const float* __restrict__ adw, float* __restrict__ Y,
        float* __restrict__ as_out, float* __restrict__ ad_out, int M) {
    constexpr int K = 128, NCOLS = 64;
    __shared__ float xs[K * 64];
    __shared__ float ws[K * 64];
    int tid = threadIdx.x;
    int row0 = blockIdx.x * 64;

    {
        int m = tid & 63;
        int kq0 = tid >> 6;
        int gr = row0 + m;
        const float4* Xv = (const float4*)(X + (size_t)gr * K);
        #pragma unroll
        for (int kq = kq0; kq < 32; kq += 4) {
            float4 v = make_float4(0.f, 0.f, 0.f, 0.f);
            if (gr < M) v = Xv[kq];
            int k = kq * 4;
            xs[(k + 0) * 64 + m] = v.x;
            xs[(k + 1) * 64 + m] = v.y;
            xs[(k + 2) * 64 + m] = v.z;
            xs[(k + 3) * 64 + m] = v.w;
        }
    }
    {
        int cq = tid & 15;
        int k0 = tid >> 4;
        #pragma unroll
        for (int k = k0; k < K; k += 16) {
            *(float4*)&ws[k * 64 + cq * 4] =
                *(const float4*)(W + (size_t)k * NCOLS + cq * 4);
        }
    }
    __syncthreads();

    int tc = tid & 15, tr = tid >> 4;
    float acc[4][4];
    #pragma unroll
    for (int i = 0; i < 4; i++)
        #pragma unroll
        for (int j = 0; j < 4; j++) acc[i][j] = 0.f;

    #pragma unroll 8
    for (int k = 0; k < K; k++) {
        float4 a = *(const float4*)&xs[k * 64 + tr * 4];
        float4 b = *(const float4*)&ws[k * 64 + tc * 4];
        float av[4] = {a.x, a.y, a.z, a.w};
        float bv[4] = {b.x, b.y, b.z, b.w};
        #pragma unroll
        for (int i = 0; i < 4; i++)
            #pragma unroll
            for (int j = 0; j < 4; j++) acc[i][j] += av[i] * bv[j];
    }

    float av[4], dv[4];
    #pragma unroll
    for (int j = 0; j < 4; j++) {
        av[j] = asw[tc * 4 + j];
        dv[j] = adw[tc * 4 + j];
    }
    #pragma unroll
    for (int i = 0; i < 4; i++) {
        float ps = acc[i][0] * av[0] + acc[i][1] * av[1] + acc[i][2] * av[2] + acc[i][3] * av[3];
        float pd = acc[i][0] * dv[0] + acc[i][1] * dv[1] + acc[i][2] * dv[2] + acc[i][3] * dv[3];
        #pragma unroll
        for (int o = 1; o < 16; o <<= 1) { ps += __shfl_xor(ps, o); pd += __shfl_xor(pd, o); }
        int gr = row0 + tr * 4 + i;
        if (gr < M) {
            if (tc == 0) { as_out[gr] = ps; ad_out[gr] = pd; }
            *(float4*)&Y[(size_t)gr * NCOLS + tc * 4] =
                make_float4(acc[i][0], acc[i][1], acc[i][2], acc[i][3]);
        }
    }
}

// ---------------- aggregates: single pass, no LDS, no max ----------------
// Wave per node. 32 lanes per edge (8B each), 2 edges per iteration, unroll x2.
// softmax shift-invariance: exp(e) directly (|e| <~ 6, safe in f32).

__global__ __launch_bounds__(256) void agg1_kernel(const uint2* __restrict__ hb,
        const float* __restrict__ asrc, const float* __restrict__ adst,
        const int* __restrict__ row_ptr, const int* __restrict__ srcs,
        const float* __restrict__ bias, float* __restrict__ out, int N) {
    int tid = threadIdx.x, wid = tid >> 6, lane = tid & 63;
    int n = blockIdx.x * 4 + wid;
    if (n >= N) return;
    int half = lane >> 5;      // which edge of the pair
    int sub  = lane & 31;      // uint2 slot within row (features 4*sub..4*sub+3)
    int head = sub >> 4;
    int start = row_ptr[n];
    int deg   = row_ptr[n + 1] - start;
    float ad = adst[n * 2 + head];

    float acc0 = 0.f, acc1 = 0.f, acc2 = 0.f, acc3 = 0.f, dsum = 0.f;
    for (int i = 0; i < deg; i += 4) {
        int e0 = i + half, e1 = i + 2 + half;
        bool v0 = e0 < deg, v1 = e1 < deg;
        int s0 = srcs[start + (v0 ? e0 : 0)];
        int s1 = srcs[start + (v1 ? e1 : 0)];
        float x0 = asrc[s0 * 2 + head] + ad;
        float x1 = asrc[s1 * 2 + head] + ad;
        uint2 u0 = hb[(size_t)s0 * 32 + sub];
        uint2 u1 = hb[(size_t)s1 * 32 + sub];
        x0 = (x0 >= 0.f) ? x0 : LRELU_SLOPE * x0;
        x1 = (x1 >= 0.f) ? x1 : LRELU_SLOPE * x1;
        float w0 = v0 ? __expf(x0) : 0.f;
        float w1 = v1 ? __expf(x1) : 0.f;
        dsum += w0 + w1;
        acc0 += w0 * bflo(u0.x) + w1 * bflo(u1.x);
        acc1 += w0 * bfhi(u0.x) + w1 * bfhi(u1.x);
        acc2 += w0 * bflo(u0.y) + w1 * bflo(u1.y);
        acc3 += w0 * bfhi(u0.y) + w1 * bfhi(u1.y);
    }
    acc0 += __shfl_xor(acc0, 32);
    acc1 += __shfl_xor(acc1, 32);
    acc2 += __shfl_xor(acc2, 32);
    acc3 += __shfl_xor(acc3, 32);
    dsum += __shfl_xor(dsum, 32);
    if (half == 0) {
        int f = sub * 4;
        float q0 = acc0 / dsum + bias[f + 0];
        float q1 = acc1 / dsum + bias[f + 1];
        float q2 = acc2 / dsum + bias[f + 2];
        float q3 = acc3 / dsum + bias[f + 3];
        q0 = (q0 > 0.f) ? q0 : __expf(q0) - 1.f;   // ELU
        q1 = (q1 > 0.f) ? q1 : __expf(q1) - 1.f;
        q2 = (q2 > 0.f) ? q2 : __expf(q2) - 1.f;
        q3 = (q3 > 0.f) ? q3 : __expf(q3) - 1.f;
        *(float4*)&out[(size_t)n * 128 + f] = make_float4(q0, q1, q2, q3);
    }
}

__global__ __launch_bounds__(256) void agg2_kernel(const float2* __restrict__ h2,
        const float* __restrict__ asrc, const float* __restrict__ adst,
        const int* __restrict__ row_ptr, const int* __restrict__ srcs,
        const float* __restrict__ bias, float* __restrict__ out, int N) {
    int tid = threadIdx.x, wid = tid >> 6, lane = tid & 63;
    int n = blockIdx.x * 4 + wid;
    if (n >= N) return;
    int half = lane >> 5;
    int sub  = lane & 31;      // float2 slot (features 2*sub, 2*sub+1)
    int start = row_ptr[n];
    int deg   = row_ptr[n + 1] - start;
    float ad = adst[n];

    float acc0 = 0.f, acc1 = 0.f, dsum = 0.f;
    for (int i = 0; i < deg; i += 4) {
        int e0 = i + half, e1 = i + 2 + half;
        bool v0 = e0 < deg, v1 = e1 < deg;
        int s0 = srcs[start + (v0 ? e0 : 0)];
        int s1 = srcs[start + (v1 ? e1 : 0)];
        float x0 = asrc[s0] + ad;
        float x1 = asrc[s1] + ad;
        float2 f0 = h2[(size_t)s0 * 32 + sub];
        float2 f1 = h2[(size_t)s1 * 32 + sub];
        x0 = (x0 >= 0.f) ? x0 : LRELU_SLOPE * x0;
        x1 = (x1 >= 0.f) ? x1 : LRELU_SLOPE * x1;
        float w0 = v0 ? __expf(x0) : 0.f;
        float w1 = v1 ? __expf(x1) : 0.f;
        dsum += w0 + w1;
        acc0 += w0 * f0.x + w1 * f1.x;
        acc1 += w0 * f0.y + w1 * f1.y;
    }
    acc0 += __shfl_xor(acc0, 32);
    acc1 += __shfl_xor(acc1, 32);
    dsum += __shfl_xor(dsum, 32);
    if (half == 0) {
        int f = sub * 2;
        *(float2*)&out[(size_t)n * 64 + f] =
            make_float2(acc0 / dsum + bias[f], acc1 / dsum + bias[f + 1]);
    }
}

// ---------------- launch ----------------

extern "C" void kernel_launch(void* const* d_in, const int* in_sizes, int n_in,
                              void* d_out, int out_size, void* d_ws, size_t ws_size,
                              hipStream_t stream) {
    const float* x    = (const float*)d_in[0];
    const int*   ei   = (const int*)d_in[1];
    const float* W1   = (const float*)d_in[2];
    const float* as1w = (const float*)d_in[3];
    const float* ad1w = (const float*)d_in[4];
    const float* b1   = (const float*)d_in[5];
    const float* W2   = (const float*)d_in[6];
    const float* as2w = (const float*)d_in[7];
    const float* ad2w = (const float*)d_in[8];
    const float* b2   = (const float*)d_in[9];
    float* out = (float*)d_out;

    const int N  = in_sizes[0] / 128;   // 50000
    const int E  = in_sizes[1] / 2;     // 600000
    const int ET = E + N;

    char* base = (char*)d_ws;
    size_t off = 0;
    auto alloc = [&](size_t bytes) -> void* {
        void* p = base + off;
        off += (bytes + 255) & ~(size_t)255;
        return p;
    };
    uint2* hb1     = (uint2*)alloc((size_t)N * 128 * 2);   // bf16 h1
    float* helu    = (float*)alloc((size_t)N * 128 * 4);
    float* h2      = (float*)alloc((size_t)N * 64 * 4);
    float* as1     = (float*)alloc((size_t)N * 2 * 4);
    float* ad1     = (float*)alloc((size_t)N * 2 * 4);
    float* as2     = (float*)alloc((size_t)N * 4);
    float* ad2     = (float*)alloc((size_t)N * 4);
    int*   deg     = (int*)alloc((size_t)N * 4);
    int*   cnt     = (int*)alloc((size_t)N * 4);
    int*   row_ptr = (int*)alloc((size_t)(N + 1) * 4);
    int*   srcs    = (int*)alloc((size_t)ET * 4);
    int*   bsum    = (int*)alloc(64 * 4);

    const int SCAN_B = (N + 1023) / 1024;

    // CSR build
    zero2_kernel<<<(N + 255) / 256, 256, 0, stream>>>(deg, cnt, N);
    degree_kernel<<<(ET + 255) / 256, 256, 0, stream>>>(ei, E, N, deg);
    scan1_kernel<<<SCAN_B, 1024, 0, stream>>>(deg, row_ptr, bsum, N);
    scan2_kernel<<<1, 64, 0, stream>>>(bsum, SCAN_B);
    scan3_kernel<<<SCAN_B, 1024, 0, stream>>>(row_ptr, bsum, deg, N);
    scatter_kernel<<<(ET + 255) / 256, 256, 0, stream>>>(ei, E, N, row_ptr, cnt, srcs);

    // layer 1: heads=2, out_dim=64, concat -> [N,128], ELU
    gemm1_kernel<<<dim3((N + 63) / 64, 2), 256, 0, stream>>>(x, W1, as1w, ad1w,
                                                             hb1, as1, ad1, N);
    agg1_kernel<<<(N + 3) / 4, 256, 0, stream>>>(hb1, as1, ad1, row_ptr, srcs,
                                                 b1, helu, N);

    // layer 2: heads=1, out_dim=64
    gemm2_kernel<<<dim3((N + 63) / 64, 1), 256, 0, stream>>>(helu, W2, as2w, ad2w,
                                                             h2, as2, ad2, N);
    agg2_kernel<<<(N + 3) / 4, 256, 0, stream>>>((const float2*)h2, as2, ad2,
                                                 row_ptr, srcs, b2, out, N);
}

// Round 5
// 183.930 us; speedup vs baseline: 1.9930x; 1.1222x over previous
//
#include <hip/hip_runtime.h>
#include <hip/hip_bf16.h>

// 2-layer GAT on MI355X. R5: GEMMs moved to MFMA (bf16 A/B, f32 acc).
// wprep pre-transposes W -> bf16 wt[n][k]; both MFMA operands read as
// contiguous ds_read_b128 with XOR-swizzled LDS (T2). Alpha fused in
// epilogue via shfl + LDS cross-wave combine. Aggregates unchanged from R4.

#define LRELU_SLOPE 0.2f

typedef __bf16 v8bf __attribute__((ext_vector_type(8)));
typedef float f32x4 __attribute__((ext_vector_type(4)));

// ---------------- CSR build ----------------

__global__ void zero2_kernel(int* __restrict__ a, int* __restrict__ b, int n) {
    int i = blockIdx.x * blockDim.x + threadIdx.x;
    if (i < n) { a[i] = 0; b[i] = 0; }
}

__global__ void degree_kernel(const int* __restrict__ ei, int E, int N,
                              int* __restrict__ deg) {
    int e = blockIdx.x * blockDim.x + threadIdx.x;
    if (e >= E + N) return;
    int d = (e < E) ? ei[E + e] : (e - E);   // self-loop edges appended
    atomicAdd(&deg[d], 1);
}

__global__ void scan1_kernel(const int* __restrict__ deg, int* __restrict__ row_ptr,
                             int* __restrict__ bsum, int n) {
    __shared__ int sm[16];
    int tid = threadIdx.x;
    int i = blockIdx.x * 1024 + tid;
    int v = (i < n) ? deg[i] : 0;
    int lane = tid & 63, wid = tid >> 6;
    int s = v;
    #pragma unroll
    for (int o = 1; o < 64; o <<= 1) { int t = __shfl_up(s, o); if (lane >= o) s += t; }
    if (lane == 63) sm[wid] = s;
    __syncthreads();
    if (tid < 16) {
        int ws = sm[tid];
        #pragma unroll
        for (int o = 1; o < 16; o <<= 1) { int t = __shfl_up(ws, o); if (tid >= o) ws += t; }
        sm[tid] = ws;
    }
    __syncthreads();
    int excl = (wid ? sm[wid - 1] : 0) + s - v;
    if (i < n) row_ptr[i] = excl;
    if (tid == 1023) bsum[blockIdx.x] = excl + v;
}

__global__ void scan2_kernel(int* __restrict__ bsum, int nb) {
    int tid = threadIdx.x;   // 64
    int v = (tid < nb) ? bsum[tid] : 0;
    int s = v;
    #pragma unroll
    for (int o = 1; o < 64; o <<= 1) { int t = __shfl_up(s, o); if (tid >= o) s += t; }
    if (tid < nb) bsum[tid] = s - v;
}

__global__ void scan3_kernel(int* __restrict__ row_ptr, const int* __restrict__ bsum,
                             const int* __restrict__ deg, int n) {
    int i = blockIdx.x * 1024 + threadIdx.x;
    if (i >= n) return;
    int val = row_ptr[i] + bsum[blockIdx.x];
    row_ptr[i] = val;
    if (i == n - 1) row_ptr[n] = val + deg[i];
}

__global__ void scatter_kernel(const int* __restrict__ ei, int E, int N,
                               const int* __restrict__ row_ptr,
                               int* __restrict__ cnt, int* __restrict__ srcs) {
    int e = blockIdx.x * blockDim.x + threadIdx.x;
    if (e >= E + N) return;
    int s, d;
    if (e < E) { s = ei[e]; d = ei[E + e]; }
    else       { s = e - E; d = s; }
    int pos = row_ptr[d] + atomicAdd(&cnt[d], 1);
    srcs[pos] = s;
}

// ---------------- bf16 helpers ----------------

__device__ __forceinline__ unsigned short bf16r(float x) {   // RNE
    unsigned u = __float_as_uint(x);
    return (unsigned short)((u + 0x7fff + ((u >> 16) & 1)) >> 16);
}
__device__ __forceinline__ unsigned pbf(float a, float b) {
    return (unsigned)bf16r(a) | ((unsigned)bf16r(b) << 16);
}
__device__ __forceinline__ float bflo(unsigned u) { return __uint_as_float(u << 16); }
__device__ __forceinline__ float bfhi(unsigned u) { return __uint_as_float(u & 0xffff0000u); }

// swizzled LDS fragment load: row stride 256B, XOR bits 4..6 by row&7 (T2)
__device__ __forceinline__ v8bf ldfrag(const char* base, int row, int kb) {
    uint4 u = *(const uint4*)(base + row * 256 + (kb ^ ((row & 7) << 4)));
    return __builtin_bit_cast(v8bf, u);
}

// ---------------- W pre-transpose + bf16 convert ----------------
// wt1[n][k] = bf16(W1[k][n]) (128x128); wt2[n][k] = bf16(W2[k][n]) (64x128).

__global__ void wprep_kernel(const float* __restrict__ W1, const float* __restrict__ W2,
                             unsigned short* __restrict__ wt1,
                             unsigned short* __restrict__ wt2) {
    int id = blockIdx.x * 256 + threadIdx.x;   // 0..767
    int n = id >> 2, kq = id & 3;
    if (n < 128) {
        #pragma unroll 8
        for (int j = 0; j < 32; j++) {
            int k = kq * 32 + j;
            wt1[n * 128 + k] = bf16r(W1[k * 128 + n]);
        }
    } else if (n < 192) {
        int n2 = n - 128;
        #pragma unroll 8
        for (int j = 0; j < 32; j++) {
            int k = kq * 32 + j;
            wt2[n2 * 128 + k] = bf16r(W2[k * 64 + n2]);
        }
    }
}

// ---------------- layer-1 MFMA GEMM + alpha + bf16 h ----------------
// Block: 64 rows x 128 cols (both heads), K=128. 4 waves; wave w owns cols
// [w*32, w*32+32) (head = w>>1), all 64 rows. acc[rt][ct] f32x4.

__global__ __launch_bounds__(256) void gemm1_kernel(const float* __restrict__ X,
        const unsigned short* __restrict__ wt, const float* __restrict__ asw,
        const float* __restrict__ adw, unsigned short* __restrict__ hb,
        float* __restrict__ as_out, float* __restrict__ ad_out, int M) {
    __shared__ uint4 xs4[1024];     // 16KB: 64 rows x 256B (bf16 k-major)
    __shared__ uint4 wt4[2048];     // 32KB: 128 rows(n) x 256B
    __shared__ float aps[4][64], apd[4][64];
    char* xs = (char*)xs4;
    char* wts = (char*)wt4;
    int t = threadIdx.x;
    int row0 = blockIdx.x * 64;
    int lane = t & 63, w = t >> 6;

    {   // stage X -> bf16 (coalesced float4 reads)
        int kq = t & 31;            // which 4-k group
        for (int m = t >> 5; m < 64; m += 8) {
            int gr = row0 + m;
            float4 v = make_float4(0.f, 0.f, 0.f, 0.f);
            if (gr < M) v = *(const float4*)(X + (size_t)gr * 128 + kq * 4);
            *(uint2*)(xs + m * 256 + ((kq * 8) ^ ((m & 7) << 4))) =
                make_uint2(pbf(v.x, v.y), pbf(v.z, v.w));
        }
    }
    {   // stage wt (already bf16, row-major [n][128])
        int slot = t & 15;
        for (int n = t >> 4; n < 128; n += 16) {
            uint4 v = *(const uint4*)(wt + (size_t)n * 128 + slot * 8);
            *(uint4*)(wts + n * 256 + ((slot * 16) ^ ((n & 7) << 4))) = v;
        }
    }
    __syncthreads();

    int l15 = lane & 15, lhi = lane >> 4;
    f32x4 acc[4][2];
    #pragma unroll
    for (int rt = 0; rt < 4; rt++) { acc[rt][0] = (f32x4)(0.f); acc[rt][1] = (f32x4)(0.f); }

    #pragma unroll
    for (int ks = 0; ks < 4; ks++) {
        int kb = ks * 64 + lhi * 16;
        v8bf b0 = ldfrag(wts, w * 32 + l15, kb);
        v8bf b1 = ldfrag(wts, w * 32 + 16 + l15, kb);
        #pragma unroll
        for (int rt = 0; rt < 4; rt++) {
            v8bf a = ldfrag(xs, rt * 16 + l15, kb);
            acc[rt][0] = __builtin_amdgcn_mfma_f32_16x16x32_bf16(a, b0, acc[rt][0], 0, 0, 0);
            acc[rt][1] = __builtin_amdgcn_mfma_f32_16x16x32_bf16(a, b1, acc[rt][1], 0, 0, 0);
        }
    }

    // epilogue: bf16 h store + per-row alpha partials
    float asv0 = asw[w * 32 + l15],      adv0 = adw[w * 32 + l15];
    float asv1 = asw[w * 32 + 16 + l15], adv1 = adw[w * 32 + 16 + l15];
    #pragma unroll
    for (int rt = 0; rt < 4; rt++) {
        #pragma unroll
        for (int r = 0; r < 4; r++) {
            int m = rt * 16 + lhi * 4 + r;
            int gr = row0 + m;
            float v0 = acc[rt][0][r], v1 = acc[rt][1][r];
            if (gr < M) {
                hb[(size_t)gr * 128 + w * 32 + l15]      = bf16r(v0);
                hb[(size_t)gr * 128 + w * 32 + 16 + l15] = bf16r(v1);
            }
            float ps = v0 * asv0 + v1 * asv1;
            float pd = v0 * adv0 + v1 * adv1;
            #pragma unroll
            for (int o = 1; o < 16; o <<= 1) { ps += __shfl_xor(ps, o); pd += __shfl_xor(pd, o); }
            if (l15 == 0) { aps[w][m] = ps; apd[w][m] = pd; }
        }
    }
    __syncthreads();
    if (t < 128) {
        int m = t & 63, hd = t >> 6;
        int gr = row0 + m;
        if (gr < M) {
            as_out[gr * 2 + hd] = aps[hd * 2][m] + aps[hd * 2 + 1][m];
            ad_out[gr * 2 + hd] = apd[hd * 2][m] + apd[hd * 2 + 1][m];
        }
    }
}

// ---------------- layer-2 MFMA GEMM + alpha (f32 h2 out) ----------------
// Block: 64 rows x 64 cols, K=128. Wave w owns cols [w*16, w*16+16).

__global__ __launch_bounds__(256) void gemm2_kernel(const float* __restrict__ X,
        const unsigned short* __restrict__ wt, const float* __restrict__ asw,
        const float* __restrict__ adw, float* __restrict__ Y,
        float* __restrict__ as_out, float* __restrict__ ad_out, int M) {
    __shared__ uint4 xs4[1024];     // 16KB
    __shared__ uint4 wt4[1024];     // 16KB: 64 rows(n) x 256B
    __shared__ float aps[4][64], apd[4][64];
    char* xs = (char*)xs4;
    char* wts = (char*)wt4;
    int t = threadIdx.x;
    int row0 = blockIdx.x * 64;
    int lane = t & 63, w = t >> 6;

    {   // stage X -> bf16
        int kq = t & 31;
        for (int m = t >> 5; m < 64; m += 8) {
            int gr = row0 + m;
            float4 v = make_float4(0.f, 0.f, 0.f, 0.f);
            if (gr < M) v = *(const float4*)(X + (size_t)gr * 128 + kq * 4);
            *(uint2*)(xs + m * 256 + ((kq * 8) ^ ((m & 7) << 4))) =
                make_uint2(pbf(v.x, v.y), pbf(v.z, v.w));
        }
    }
    {   // stage wt2
        int slot = t & 15;
        for (int n = t >> 4; n < 64; n += 16) {
            uint4 v = *(const uint4*)(wt + (size_t)n * 128 + slot * 8);
            *(uint4*)(wts + n * 256 + ((slot * 16) ^ ((n & 7) << 4))) = v;
        }
    }
    __syncthreads();

    int l15 = lane & 15, lhi = lane >> 4;
    f32x4 acc[4];
    #pragma unroll
    for (int rt = 0; rt < 4; rt++) acc[rt] = (f32x4)(0.f);

    #pragma unroll
    for (int ks = 0; ks < 4; ks++) {
        int kb = ks * 64 + lhi * 16;
        v8bf b0 = ldfrag(wts, w * 16 + l15, kb);
        #pragma unroll
        for (int rt = 0; rt < 4; rt++) {
            v8bf a = ldfrag(xs, rt * 16 + l15, kb);
            acc[rt] = __builtin_amdgcn_mfma_f32_16x16x32_bf16(a, b0, acc[rt], 0, 0, 0);
        }
    }

    float asv = asw[w * 16 + l15], adv = adw[w * 16 + l15];
    #pragma unroll
    for (int rt = 0; rt < 4; rt++) {
        #pragma unroll
        for (int r = 0; r < 4; r++) {
            int m = rt * 16 + lhi * 4 + r;
            int gr = row0 + m;
            float v0 = acc[rt][r];
            if (gr < M) Y[(size_t)gr * 64 + w * 16 + l15] = v0;
            float ps = v0 * asv;
            float pd = v0 * adv;
            #pragma unroll
            for (int o = 1; o < 16; o <<= 1) { ps += __shfl_xor(ps, o); pd += __shfl_xor(pd, o); }
            if (l15 == 0) { aps[w][m] = ps; apd[w][m] = pd; }
        }
    }
    __syncthreads();
    if (t < 64) {
        int gr = row0 + t;
        if (gr < M) {
            as_out[gr] = aps[0][t] + aps[1][t] + aps[2][t] + aps[3][t];
            ad_out[gr] = apd[0][t] + apd[1][t] + apd[2][t] + apd[3][t];
        }
    }
}

// ---------------- aggregates (unchanged from R4) ----------------

__global__ __launch_bounds__(256) void agg1_kernel(const uint2* __restrict__ hb,
        const float* __restrict__ asrc, const float* __restrict__ adst,
        const int* __restrict__ row_ptr, const int* __restrict__ srcs,
        const float* __restrict__ bias, float* __restrict__ out, int N) {
    int tid = threadIdx.x, wid = tid >> 6, lane = tid & 63;
    int n = blockIdx.x * 4 + wid;
    if (n >= N) return;
    int half = lane >> 5;
    int sub  = lane & 31;
    int head = sub >> 4;
    int start = row_ptr[n];
    int deg   = row_ptr[n + 1] - start;
    float ad = adst[n * 2 + head];

    float acc0 = 0.f, acc1 = 0.f, acc2 = 0.f, acc3 = 0.f, dsum = 0.f;
    for (int i = 0; i < deg; i += 4) {
        int e0 = i + half, e1 = i + 2 + half;
        bool v0 = e0 < deg, v1 = e1 < deg;
        int s0 = srcs[start + (v0 ? e0 : 0)];
        int s1 = srcs[start + (v1 ? e1 : 0)];
        float x0 = asrc[s0 * 2 + head] + ad;
        float x1 = asrc[s1 * 2 + head] + ad;
        uint2 u0 = hb[(size_t)s0 * 32 + sub];
        uint2 u1 = hb[(size_t)s1 * 32 + sub];
        x0 = (x0 >= 0.f) ? x0 : LRELU_SLOPE * x0;
        x1 = (x1 >= 0.f) ? x1 : LRELU_SLOPE * x1;
        float w0 = v0 ? __expf(x0) : 0.f;
        float w1 = v1 ? __expf(x1) : 0.f;
        dsum += w0 + w1;
        acc0 += w0 * bflo(u0.x) + w1 * bflo(u1.x);
        acc1 += w0 * bfhi(u0.x) + w1 * bfhi(u1.x);
        acc2 += w0 * bflo(u0.y) + w1 * bflo(u1.y);
        acc3 += w0 * bfhi(u0.y) + w1 * bfhi(u1.y);
    }
    acc0 += __shfl_xor(acc0, 32);
    acc1 += __shfl_xor(acc1, 32);
    acc2 += __shfl_xor(acc2, 32);
    acc3 += __shfl_xor(acc3, 32);
    dsum += __shfl_xor(dsum, 32);
    if (half == 0) {
        int f = sub * 4;
        float q0 = acc0 / dsum + bias[f + 0];
        float q1 = acc1 / dsum + bias[f + 1];
        float q2 = acc2 / dsum + bias[f + 2];
        float q3 = acc3 / dsum + bias[f + 3];
        q0 = (q0 > 0.f) ? q0 : __expf(q0) - 1.f;   // ELU
        q1 = (q1 > 0.f) ? q1 : __expf(q1) - 1.f;
        q2 = (q2 > 0.f) ? q2 : __expf(q2) - 1.f;
        q3 = (q3 > 0.f) ? q3 : __expf(q3) - 1.f;
        *(float4*)&out[(size_t)n * 128 + f] = make_float4(q0, q1, q2, q3);
    }
}

__global__ __launch_bounds__(256) void agg2_kernel(const float2* __restrict__ h2,
        const float* __restrict__ asrc, const float* __restrict__ adst,
        const int* __restrict__ row_ptr, const int* __restrict__ srcs,
        const float* __restrict__ bias, float* __restrict__ out, int N) {
    int tid = threadIdx.x, wid = tid >> 6, lane = tid & 63;
    int n = blockIdx.x * 4 + wid;
    if (n >= N) return;
    int half = lane >> 5;
    int sub  = lane & 31;
    int start = row_ptr[n];
    int deg   = row_ptr[n + 1] - start;
    float ad = adst[n];

    float acc0 = 0.f, acc1 = 0.f, dsum = 0.f;
    for (int i = 0; i < deg; i += 4) {
        int e0 = i + half, e1 = i + 2 + half;
        bool v0 = e0 < deg, v1 = e1 < deg;
        int s0 = srcs[start + (v0 ? e0 : 0)];
        int s1 = srcs[start + (v1 ? e1 : 0)];
        float x0 = asrc[s0] + ad;
        float x1 = asrc[s1] + ad;
        float2 f0 = h2[(size_t)s0 * 32 + sub];
        float2 f1 = h2[(size_t)s1 * 32 + sub];
        x0 = (x0 >= 0.f) ? x0 : LRELU_SLOPE * x0;
        x1 = (x1 >= 0.f) ? x1 : LRELU_SLOPE * x1;
        float w0 = v0 ? __expf(x0) : 0.f;
        float w1 = v1 ? __expf(x1) : 0.f;
        dsum += w0 + w1;
        acc0 += w0 * f0.x + w1 * f1.x;
        acc1 += w0 * f0.y + w1 * f1.y;
    }
    acc0 += __shfl_xor(acc0, 32);
    acc1 += __shfl_xor(acc1, 32);
    dsum += __shfl_xor(dsum, 32);
    if (half == 0) {
        int f = sub * 2;
        *(float2*)&out[(size_t)n * 64 + f] =
            make_float2(acc0 / dsum + bias[f], acc1 / dsum + bias[f + 1]);
    }
}

// ---------------- launch ----------------

extern "C" void kernel_launch(void* const* d_in, const int* in_sizes, int n_in,
                              void* d_out, int out_size, void* d_ws, size_t ws_size,
                              hipStream_t stream) {
    const float* x    = (const float*)d_in[0];
    const int*   ei   = (const int*)d_in[1];
    const float* W1   = (const float*)d_in[2];
    const float* as1w = (const float*)d_in[3];
    const float* ad1w = (const float*)d_in[4];
    const float* b1   = (const float*)d_in[5];
    const float* W2   = (const float*)d_in[6];
    const float* as2w = (const float*)d_in[7];
    const float* ad2w = (const float*)d_in[8];
    const float* b2   = (const float*)d_in[9];
    float* out = (float*)d_out;

    const int N  = in_sizes[0] / 128;   // 50000
    const int E  = in_sizes[1] / 2;     // 600000
    const int ET = E + N;

    char* base = (char*)d_ws;
    size_t off = 0;
    auto alloc = [&](size_t bytes) -> void* {
        void* p = base + off;
        off += (bytes + 255) & ~(size_t)255;
        return p;
    };
    unsigned short* hb1 = (unsigned short*)alloc((size_t)N * 128 * 2);  // bf16 h1
    float* helu    = (float*)alloc((size_t)N * 128 * 4);
    float* h2      = (float*)alloc((size_t)N * 64 * 4);
    float* as1     = (float*)alloc((size_t)N * 2 * 4);
    float* ad1     = (float*)alloc((size_t)N * 2 * 4);
    float* as2     = (float*)alloc((size_t)N * 4);
    float* ad2     = (float*)alloc((size_t)N * 4);
    int*   deg     = (int*)alloc((size_t)N * 4);
    int*   cnt     = (int*)alloc((size_t)N * 4);
    int*   row_ptr = (int*)alloc((size_t)(N + 1) * 4);
    int*   srcs    = (int*)alloc((size_t)ET * 4);
    int*   bsum    = (int*)alloc(64 * 4);
    unsigned short* wt1 = (unsigned short*)alloc(128 * 128 * 2);
    unsigned short* wt2 = (unsigned short*)alloc(64 * 128 * 2);

    const int SCAN_B = (N + 1023) / 1024;

    // W prep + CSR build
    wprep_kernel<<<3, 256, 0, stream>>>(W1, W2, wt1, wt2);
    zero2_kernel<<<(N + 255) / 256, 256, 0, stream>>>(deg, cnt, N);
    degree_kernel<<<(ET + 255) / 256, 256, 0, stream>>>(ei, E, N, deg);
    scan1_kernel<<<SCAN_B, 1024, 0, stream>>>(deg, row_ptr, bsum, N);
    scan2_kernel<<<1, 64, 0, stream>>>(bsum, SCAN_B);
    scan3_kernel<<<SCAN_B, 1024, 0, stream>>>(row_ptr, bsum, deg, N);
    scatter_kernel<<<(ET + 255) / 256, 256, 0, stream>>>(ei, E, N, row_ptr, cnt, srcs);

    // layer 1: heads=2, out_dim=64, concat -> [N,128], ELU
    gemm1_kernel<<<(N + 63) / 64, 256, 0, stream>>>(x, wt1, as1w, ad1w,
                                                    hb1, as1, ad1, N);
    agg1_kernel<<<(N + 3) / 4, 256, 0, stream>>>((const uint2*)hb1, as1, ad1,
                                                 row_ptr, srcs, b1, helu, N);

    // layer 2: heads=1, out_dim=64
    gemm2_kernel<<<(N + 63) / 64, 256, 0, stream>>>(helu, wt2, as2w, ad2w,
                                                    h2, as2, ad2, N);
    agg2_kernel<<<(N + 3) / 4, 256, 0, stream>>>((const float2*)h2, as2, ad2,
                                                 row_ptr, srcs, b2, out, N);
}

// Round 6
// 173.708 us; speedup vs baseline: 2.1103x; 1.0588x over previous
//
#include <hip/hip_runtime.h>
#include <hip/hip_bf16.h>

// 2-layer GAT on MI355X. R6: phase-split aggregates (edge-parallel exp, then
// 16-lane x 16B feature gather with shfl-distributed weights, 8 edges in
// flight). MFMA GEMMs + fused alpha epilogue (R5) unchanged.

#define LRELU_SLOPE 0.2f

typedef __bf16 v8bf __attribute__((ext_vector_type(8)));
typedef float f32x4 __attribute__((ext_vector_type(4)));

// ---------------- CSR build ----------------

__global__ void zero2_kernel(int* __restrict__ a, int* __restrict__ b, int n) {
    int i = blockIdx.x * blockDim.x + threadIdx.x;
    if (i < n) { a[i] = 0; b[i] = 0; }
}

__global__ void degree_kernel(const int* __restrict__ ei, int E, int N,
                              int* __restrict__ deg) {
    int e = blockIdx.x * blockDim.x + threadIdx.x;
    if (e >= E + N) return;
    int d = (e < E) ? ei[E + e] : (e - E);   // self-loop edges appended
    atomicAdd(&deg[d], 1);
}

__global__ void scan1_kernel(const int* __restrict__ deg, int* __restrict__ row_ptr,
                             int* __restrict__ bsum, int n) {
    __shared__ int sm[16];
    int tid = threadIdx.x;
    int i = blockIdx.x * 1024 + tid;
    int v = (i < n) ? deg[i] : 0;
    int lane = tid & 63, wid = tid >> 6;
    int s = v;
    #pragma unroll
    for (int o = 1; o < 64; o <<= 1) { int t = __shfl_up(s, o); if (lane >= o) s += t; }
    if (lane == 63) sm[wid] = s;
    __syncthreads();
    if (tid < 16) {
        int ws = sm[tid];
        #pragma unroll
        for (int o = 1; o < 16; o <<= 1) { int t = __shfl_up(ws, o); if (tid >= o) ws += t; }
        sm[tid] = ws;
    }
    __syncthreads();
    int excl = (wid ? sm[wid - 1] : 0) + s - v;
    if (i < n) row_ptr[i] = excl;
    if (tid == 1023) bsum[blockIdx.x] = excl + v;
}

__global__ void scan2_kernel(int* __restrict__ bsum, int nb) {
    int tid = threadIdx.x;   // 64
    int v = (tid < nb) ? bsum[tid] : 0;
    int s = v;
    #pragma unroll
    for (int o = 1; o < 64; o <<= 1) { int t = __shfl_up(s, o); if (tid >= o) s += t; }
    if (tid < nb) bsum[tid] = s - v;
}

__global__ void scan3_kernel(int* __restrict__ row_ptr, const int* __restrict__ bsum,
                             const int* __restrict__ deg, int n) {
    int i = blockIdx.x * 1024 + threadIdx.x;
    if (i >= n) return;
    int val = row_ptr[i] + bsum[blockIdx.x];
    row_ptr[i] = val;
    if (i == n - 1) row_ptr[n] = val + deg[i];
}

__global__ void scatter_kernel(const int* __restrict__ ei, int E, int N,
                               const int* __restrict__ row_ptr,
                               int* __restrict__ cnt, int* __restrict__ srcs) {
    int e = blockIdx.x * blockDim.x + threadIdx.x;
    if (e >= E + N) return;
    int s, d;
    if (e < E) { s = ei[e]; d = ei[E + e]; }
    else       { s = e - E; d = s; }
    int pos = row_ptr[d] + atomicAdd(&cnt[d], 1);
    srcs[pos] = s;
}

// ---------------- bf16 helpers ----------------

__device__ __forceinline__ unsigned short bf16r(float x) {   // RNE
    unsigned u = __float_as_uint(x);
    return (unsigned short)((u + 0x7fff + ((u >> 16) & 1)) >> 16);
}
__device__ __forceinline__ unsigned pbf(float a, float b) {
    return (unsigned)bf16r(a) | ((unsigned)bf16r(b) << 16);
}
__device__ __forceinline__ float bflo(unsigned u) { return __uint_as_float(u << 16); }
__device__ __forceinline__ float bfhi(unsigned u) { return __uint_as_float(u & 0xffff0000u); }

// swizzled LDS fragment load: row stride 256B, XOR bits 4..6 by row&7 (T2)
__device__ __forceinline__ v8bf ldfrag(const char* base, int row, int kb) {
    uint4 u = *(const uint4*)(base + row * 256 + (kb ^ ((row & 7) << 4)));
    return __builtin_bit_cast(v8bf, u);
}

// ---------------- W pre-transpose + bf16 convert ----------------

__global__ void wprep_kernel(const float* __restrict__ W1, const float* __restrict__ W2,
                             unsigned short* __restrict__ wt1,
                             unsigned short* __restrict__ wt2) {
    int id = blockIdx.x * 256 + threadIdx.x;   // 0..767
    int n = id >> 2, kq = id & 3;
    if (n < 128) {
        #pragma unroll 8
        for (int j = 0; j < 32; j++) {
            int k = kq * 32 + j;
            wt1[n * 128 + k] = bf16r(W1[k * 128 + n]);
        }
    } else if (n < 192) {
        int n2 = n - 128;
        #pragma unroll 8
        for (int j = 0; j < 32; j++) {
            int k = kq * 32 + j;
            wt2[n2 * 128 + k] = bf16r(W2[k * 64 + n2]);
        }
    }
}

// ---------------- layer-1 MFMA GEMM + alpha + bf16 h (R5) ----------------

__global__ __launch_bounds__(256) void gemm1_kernel(const float* __restrict__ X,
        const unsigned short* __restrict__ wt, const float* __restrict__ asw,
        const float* __restrict__ adw, unsigned short* __restrict__ hb,
        float* __restrict__ as_out, float* __restrict__ ad_out, int M) {
    __shared__ uint4 xs4[1024];     // 16KB: 64 rows x 256B (bf16 k-major)
    __shared__ uint4 wt4[2048];     // 32KB: 128 rows(n) x 256B
    __shared__ float aps[4][64], apd[4][64];
    char* xs = (char*)xs4;
    char* wts = (char*)wt4;
    int t = threadIdx.x;
    int row0 = blockIdx.x * 64;
    int lane = t & 63, w = t >> 6;

    {   // stage X -> bf16 (coalesced float4 reads)
        int kq = t & 31;
        for (int m = t >> 5; m < 64; m += 8) {
            int gr = row0 + m;
            float4 v = make_float4(0.f, 0.f, 0.f, 0.f);
            if (gr < M) v = *(const float4*)(X + (size_t)gr * 128 + kq * 4);
            *(uint2*)(xs + m * 256 + ((kq * 8) ^ ((m & 7) << 4))) =
                make_uint2(pbf(v.x, v.y), pbf(v.z, v.w));
        }
    }
    {   // stage wt (already bf16, row-major [n][128])
        int slot = t & 15;
        for (int n = t >> 4; n < 128; n += 16) {
            uint4 v = *(const uint4*)(wt + (size_t)n * 128 + slot * 8);
            *(uint4*)(wts + n * 256 + ((slot * 16) ^ ((n & 7) << 4))) = v;
        }
    }
    __syncthreads();

    int l15 = lane & 15, lhi = lane >> 4;
    f32x4 acc[4][2];
    #pragma unroll
    for (int rt = 0; rt < 4; rt++) { acc[rt][0] = (f32x4)(0.f); acc[rt][1] = (f32x4)(0.f); }

    #pragma unroll
    for (int ks = 0; ks < 4; ks++) {
        int kb = ks * 64 + lhi * 16;
        v8bf b0 = ldfrag(wts, w * 32 + l15, kb);
        v8bf b1 = ldfrag(wts, w * 32 + 16 + l15, kb);
        #pragma unroll
        for (int rt = 0; rt < 4; rt++) {
            v8bf a = ldfrag(xs, rt * 16 + l15, kb);
            acc[rt][0] = __builtin_amdgcn_mfma_f32_16x16x32_bf16(a, b0, acc[rt][0], 0, 0, 0);
            acc[rt][1] = __builtin_amdgcn_mfma_f32_16x16x32_bf16(a, b1, acc[rt][1], 0, 0, 0);
        }
    }

    float asv0 = asw[w * 32 + l15],      adv0 = adw[w * 32 + l15];
    float asv1 = asw[w * 32 + 16 + l15], adv1 = adw[w * 32 + 16 + l15];
    #pragma unroll
    for (int rt = 0; rt < 4; rt++) {
        #pragma unroll
        for (int r = 0; r < 4; r++) {
            int m = rt * 16 + lhi * 4 + r;
            int gr = row0 + m;
            float v0 = acc[rt][0][r], v1 = acc[rt][1][r];
            if (gr < M) {
                hb[(size_t)gr * 128 + w * 32 + l15]      = bf16r(v0);
                hb[(size_t)gr * 128 + w * 32 + 16 + l15] = bf16r(v1);
            }
            float ps = v0 * asv0 + v1 * asv1;
            float pd = v0 * adv0 + v1 * adv1;
            #pragma unroll
            for (int o = 1; o < 16; o <<= 1) { ps += __shfl_xor(ps, o); pd += __shfl_xor(pd, o); }
            if (l15 == 0) { aps[w][m] = ps; apd[w][m] = pd; }
        }
    }
    __syncthreads();
    if (t < 128) {
        int m = t & 63, hd = t >> 6;
        int gr = row0 + m;
        if (gr < M) {
            as_out[gr * 2 + hd] = aps[hd * 2][m] + aps[hd * 2 + 1][m];
            ad_out[gr * 2 + hd] = apd[hd * 2][m] + apd[hd * 2 + 1][m];
        }
    }
}

// ---------------- layer-2 MFMA GEMM + alpha (f32 h2 out) (R5) ----------------

__global__ __launch_bounds__(256) void gemm2_kernel(const float* __restrict__ X,
        const unsigned short* __restrict__ wt, const float* __restrict__ asw,
        const float* __restrict__ adw, float* __restrict__ Y,
        float* __restrict__ as_out, float* __restrict__ ad_out, int M) {
    __shared__ uint4 xs4[1024];
    __shared__ uint4 wt4[1024];
    __shared__ float aps[4][64], apd[4][64];
    char* xs = (char*)xs4;
    char* wts = (char*)wt4;
    int t = threadIdx.x;
    int row0 = blockIdx.x * 64;
    int lane = t & 63, w = t >> 6;

    {
        int kq = t & 31;
        for (int m = t >> 5; m < 64; m += 8) {
            int gr = row0 + m;
            float4 v = make_float4(0.f, 0.f, 0.f, 0.f);
            if (gr < M) v = *(const float4*)(X + (size_t)gr * 128 + kq * 4);
            *(uint2*)(xs + m * 256 + ((kq * 8) ^ ((m & 7) << 4))) =
                make_uint2(pbf(v.x, v.y), pbf(v.z, v.w));
        }
    }
    {
        int slot = t & 15;
        for (int n = t >> 4; n < 64; n += 16) {
            uint4 v = *(const uint4*)(wt + (size_t)n * 128 + slot * 8);
            *(uint4*)(wts + n * 256 + ((slot * 16) ^ ((n & 7) << 4))) = v;
        }
    }
    __syncthreads();

    int l15 = lane & 15, lhi = lane >> 4;
    f32x4 acc[4];
    #pragma unroll
    for (int rt = 0; rt < 4; rt++) acc[rt] = (f32x4)(0.f);

    #pragma unroll
    for (int ks = 0; ks < 4; ks++) {
        int kb = ks * 64 + lhi * 16;
        v8bf b0 = ldfrag(wts, w * 16 + l15, kb);
        #pragma unroll
        for (int rt = 0; rt < 4; rt++) {
            v8bf a = ldfrag(xs, rt * 16 + l15, kb);
            acc[rt] = __builtin_amdgcn_mfma_f32_16x16x32_bf16(a, b0, acc[rt], 0, 0, 0);
        }
    }

    float asv = asw[w * 16 + l15], adv = adw[w * 16 + l15];
    #pragma unroll
    for (int rt = 0; rt < 4; rt++) {
        #pragma unroll
        for (int r = 0; r < 4; r++) {
            int m = rt * 16 + lhi * 4 + r;
            int gr = row0 + m;
            float v0 = acc[rt][r];
            if (gr < M) Y[(size_t)gr * 64 + w * 16 + l15] = v0;
            float ps = v0 * asv;
            float pd = v0 * adv;
            #pragma unroll
            for (int o = 1; o < 16; o <<= 1) { ps += __shfl_xor(ps, o); pd += __shfl_xor(pd, o); }
            if (l15 == 0) { aps[w][m] = ps; apd[w][m] = pd; }
        }
    }
    __syncthreads();
    if (t < 64) {
        int gr = row0 + t;
        if (gr < M) {
            as_out[gr] = aps[0][t] + aps[1][t] + aps[2][t] + aps[3][t];
            ad_out[gr] = apd[0][t] + apd[1][t] + apd[2][t] + apd[3][t];
        }
    }
}

// ---------------- aggregates: phase-split (R6) ----------------
// Phase A: lane e owns edge e (<=64/pass): srcs + asrc gather + lrelu + exp
// ONCE per edge. Phase B: 16 lanes x 16B per edge row, 4 edge slots/wave,
// 2 independent gathers per iteration (8 edges in flight), weights via shfl.

__global__ __launch_bounds__(256) void agg1_kernel(const uint4* __restrict__ hb,
        const float2* __restrict__ asrc, const float2* __restrict__ adst,
        const int* __restrict__ row_ptr, const int* __restrict__ srcs,
        const float* __restrict__ bias, float* __restrict__ out, int N) {
    int tid = threadIdx.x, wid = tid >> 6, lane = tid & 63;
    int n = blockIdx.x * 4 + wid;
    if (n >= N) return;
    int chunk = lane & 15;     // 16B chunk of the 256B row (features chunk*8..+8)
    int slot  = lane >> 4;     // edge slot 0..3
    int start = row_ptr[n];
    int deg   = row_ptr[n + 1] - start;
    float2 ad = adst[n];

    float acc[8];
    #pragma unroll
    for (int k = 0; k < 8; k++) acc[k] = 0.f;
    float dsum0 = 0.f, dsum1 = 0.f;

    for (int base = 0; base < deg; base += 64) {
        int cnt = min(64, deg - base);
        int s = 0; float w0 = 0.f, w1 = 0.f;
        if (lane < cnt) {
            s = srcs[start + base + lane];
            float2 av = asrc[s];
            float e0 = av.x + ad.x; e0 = (e0 >= 0.f) ? e0 : LRELU_SLOPE * e0;
            float e1 = av.y + ad.y; e1 = (e1 >= 0.f) ? e1 : LRELU_SLOPE * e1;
            w0 = __expf(e0); w1 = __expf(e1);
        }
        dsum0 += w0; dsum1 += w1;

        for (int j0 = 0; j0 < cnt; j0 += 8) {
            int ea = j0 + slot, eb = j0 + 4 + slot;
            int sa = __shfl(s, ea), sb = __shfl(s, eb);
            float wa0 = __shfl(w0, ea), wa1 = __shfl(w1, ea);
            float wb0 = __shfl(w0, eb), wb1 = __shfl(w1, eb);
            float wa = (chunk >= 8) ? wa1 : wa0;
            float wb = (chunk >= 8) ? wb1 : wb0;
            uint4 ua = make_uint4(0, 0, 0, 0), ub = make_uint4(0, 0, 0, 0);
            if (ea < cnt) ua = hb[(size_t)sa * 16 + chunk];
            if (eb < cnt) ub = hb[(size_t)sb * 16 + chunk];
            acc[0] += wa * bflo(ua.x) + wb * bflo(ub.x);
            acc[1] += wa * bfhi(ua.x) + wb * bfhi(ub.x);
            acc[2] += wa * bflo(ua.y) + wb * bflo(ub.y);
            acc[3] += wa * bfhi(ua.y) + wb * bfhi(ub.y);
            acc[4] += wa * bflo(ua.z) + wb * bflo(ub.z);
            acc[5] += wa * bfhi(ua.z) + wb * bfhi(ub.z);
            acc[6] += wa * bflo(ua.w) + wb * bflo(ub.w);
            acc[7] += wa * bfhi(ua.w) + wb * bfhi(ub.w);
        }
    }

    #pragma unroll
    for (int k = 0; k < 8; k++) {
        acc[k] += __shfl_xor(acc[k], 16);
        acc[k] += __shfl_xor(acc[k], 32);
    }
    #pragma unroll
    for (int o = 1; o < 64; o <<= 1) {
        dsum0 += __shfl_xor(dsum0, o);
        dsum1 += __shfl_xor(dsum1, o);
    }
    if (slot == 0) {
        float inv = 1.f / ((chunk >= 8) ? dsum1 : dsum0);
        int f = chunk * 8;
        float q[8];
        #pragma unroll
        for (int k = 0; k < 8; k++) {
            q[k] = acc[k] * inv + bias[f + k];
            q[k] = (q[k] > 0.f) ? q[k] : __expf(q[k]) - 1.f;   // ELU
        }
        *(float4*)&out[(size_t)n * 128 + f]     = make_float4(q[0], q[1], q[2], q[3]);
        *(float4*)&out[(size_t)n * 128 + f + 4] = make_float4(q[4], q[5], q[6], q[7]);
    }
}

__global__ __launch_bounds__(256) void agg2_kernel(const float4* __restrict__ h2,
        const float* __restrict__ asrc, const float* __restrict__ adst,
        const int* __restrict__ row_ptr, const int* __restrict__ srcs,
        const float* __restrict__ bias, float* __restrict__ out, int N) {
    int tid = threadIdx.x, wid = tid >> 6, lane = tid & 63;
    int n = blockIdx.x * 4 + wid;
    if (n >= N) return;
    int chunk = lane & 15;     // float4 chunk (features chunk*4..+4)
    int slot  = lane >> 4;
    int start = row_ptr[n];
    int deg   = row_ptr[n + 1] - start;
    float ad = adst[n];

    float acc[4];
    #pragma unroll
    for (int k = 0; k < 4; k++) acc[k] = 0.f;
    float dsum = 0.f;

    for (int base = 0; base < deg; base += 64) {
        int cnt = min(64, deg - base);
        int s = 0; float w = 0.f;
        if (lane < cnt) {
            s = srcs[start + base + lane];
            float e = asrc[s] + ad;
            e = (e >= 0.f) ? e : LRELU_SLOPE * e;
            w = __expf(e);
        }
        dsum += w;

        for (int j0 = 0; j0 < cnt; j0 += 8) {
            int ea = j0 + slot, eb = j0 + 4 + slot;
            int sa = __shfl(s, ea), sb = __shfl(s, eb);
            float wa = __shfl(w, ea), wb = __shfl(w, eb);
            float4 fa = make_float4(0.f, 0.f, 0.f, 0.f);
            float4 fb = make_float4(0.f, 0.f, 0.f, 0.f);
            if (ea < cnt) fa = h2[(size_t)sa * 16 + chunk];
            if (eb < cnt) fb = h2[(size_t)sb * 16 + chunk];
            acc[0] += wa * fa.x + wb * fb.x;
            acc[1] += wa * fa.y + wb * fb.y;
            acc[2] += wa * fa.z + wb * fb.z;
            acc[3] += wa * fa.w + wb * fb.w;
        }
    }

    #pragma unroll
    for (int k = 0; k < 4; k++) {
        acc[k] += __shfl_xor(acc[k], 16);
        acc[k] += __shfl_xor(acc[k], 32);
    }
    #pragma unroll
    for (int o = 1; o < 64; o <<= 1) dsum += __shfl_xor(dsum, o);
    if (slot == 0) {
        float inv = 1.f / dsum;
        int f = chunk * 4;
        *(float4*)&out[(size_t)n * 64 + f] = make_float4(
            acc[0] * inv + bias[f + 0], acc[1] * inv + bias[f + 1],
            acc[2] * inv + bias[f + 2], acc[3] * inv + bias[f + 3]);
    }
}

// ---------------- launch ----------------

extern "C" void kernel_launch(void* const* d_in, const int* in_sizes, int n_in,
                              void* d_out, int out_size, void* d_ws, size_t ws_size,
                              hipStream_t stream) {
    const float* x    = (const float*)d_in[0];
    const int*   ei   = (const int*)d_in[1];
    const float* W1   = (const float*)d_in[2];
    const float* as1w = (const float*)d_in[3];
    const float* ad1w = (const float*)d_in[4];
    const float* b1   = (const float*)d_in[5];
    const float* W2   = (const float*)d_in[6];
    const float* as2w = (const float*)d_in[7];
    const float* ad2w = (const float*)d_in[8];
    const float* b2   = (const float*)d_in[9];
    float* out = (float*)d_out;

    const int N  = in_sizes[0] / 128;   // 50000
    const int E  = in_sizes[1] / 2;     // 600000
    const int ET = E + N;

    char* base = (char*)d_ws;
    size_t off = 0;
    auto alloc = [&](size_t bytes) -> void* {
        void* p = base + off;
        off += (bytes + 255) & ~(size_t)255;
        return p;
    };
    unsigned short* hb1 = (unsigned short*)alloc((size_t)N * 128 * 2);  // bf16 h1
    float* helu    = (float*)alloc((size_t)N * 128 * 4);
    float* h2      = (float*)alloc((size_t)N * 64 * 4);
    float* as1     = (float*)alloc((size_t)N * 2 * 4);
    float* ad1     = (float*)alloc((size_t)N * 2 * 4);
    float* as2     = (float*)alloc((size_t)N * 4);
    float* ad2     = (float*)alloc((size_t)N * 4);
    int*   deg     = (int*)alloc((size_t)N * 4);
    int*   cnt     = (int*)alloc((size_t)N * 4);
    int*   row_ptr = (int*)alloc((size_t)(N + 1) * 4);
    int*   srcs    = (int*)alloc((size_t)ET * 4);
    int*   bsum    = (int*)alloc(64 * 4);
    unsigned short* wt1 = (unsigned short*)alloc(128 * 128 * 2);
    unsigned short* wt2 = (unsigned short*)alloc(64 * 128 * 2);

    const int SCAN_B = (N + 1023) / 1024;

    // W prep + CSR build
    wprep_kernel<<<3, 256, 0, stream>>>(W1, W2, wt1, wt2);
    zero2_kernel<<<(N + 255) / 256, 256, 0, stream>>>(deg, cnt, N);
    degree_kernel<<<(ET + 255) / 256, 256, 0, stream>>>(ei, E, N, deg);
    scan1_kernel<<<SCAN_B, 1024, 0, stream>>>(deg, row_ptr, bsum, N);
    scan2_kernel<<<1, 64, 0, stream>>>(bsum, SCAN_B);
    scan3_kernel<<<SCAN_B, 1024, 0, stream>>>(row_ptr, bsum, deg, N);
    scatter_kernel<<<(ET + 255) / 256, 256, 0, stream>>>(ei, E, N, row_ptr, cnt, srcs);

    // layer 1: heads=2, out_dim=64, concat -> [N,128], ELU
    gemm1_kernel<<<(N + 63) / 64, 256, 0, stream>>>(x, wt1, as1w, ad1w,
                                                    hb1, as1, ad1, N);
    agg1_kernel<<<(N + 3) / 4, 256, 0, stream>>>((const uint4*)hb1,
                                                 (const float2*)as1, (const float2*)ad1,
                                                 row_ptr, srcs, b1, helu, N);

    // layer 2: heads=1, out_dim=64
    gemm2_kernel<<<(N + 63) / 64, 256, 0, stream>>>(helu, wt2, as2w, ad2w,
                                                    h2, as2, ad2, N);
    agg2_kernel<<<(N + 3) / 4, 256, 0, stream>>>((const float4*)h2, as2, ad2,
                                                 row_ptr, srcs, b2, out, N);
}